// Round 1
// baseline (65.539 us; speedup 1.0000x reference)
//
#include <hip/hip_runtime.h>

// CTC forward loss, B=512, T=512, C=81 (blank=80), L=64, S=129.
// One wave per batch element; lane l holds states 2l (a0), 2l+1 (a1);
// lane 63 also holds state 128 (a2). Log2-domain throughout; *ln2 at end.

#define TSTEPS 512
#define NCLS   81
#define LMAX   64
#define PADTOK 99
#define NEGF   (-1e30f)
#define EPSF   1e-7f
#define UU     16            // steps per prefetch chunk (regs: 4*UU floats)

#if __has_builtin(__builtin_amdgcn_exp2f)
#define FEXP2 __builtin_amdgcn_exp2f
#else
#define FEXP2 exp2f
#endif
#if __has_builtin(__builtin_amdgcn_logf)
#define FLOG2 __builtin_amdgcn_logf
#else
#define FLOG2 log2f
#endif

__global__ __launch_bounds__(64) void ctc_kernel(
    const int* __restrict__ y_true, const float* __restrict__ y_pred,
    float* __restrict__ out)
{
  const int b    = blockIdx.x;
  const int lane = threadIdx.x;
  const float* __restrict__ yp = y_pred + (size_t)b * (TSTEPS * NCLS);

  // label length (padding is a contiguous tail by construction), label per lane
  const int  yt  = y_true[b * LMAX + lane];
  const bool mk  = (yt != PADTOK);
  const int  len = __popcll(__ballot(mk));
  const int  lab = mk ? yt : 0;
  const int  labu  = __shfl_up(lab, 1);
  const bool allow = (lane >= 1) && (lab != labu);   // skip-transition for odd state 2l+1

  float a0, a1, a2;
  float pbA[UU], plA[UU], pbB[UU], plB[UU];

#define LOADC(pb, pl, tb) do { \
    _Pragma("unroll") \
    for (int u = 0; u < UU; ++u) { \
      const int tt = (tb) + u; \
      pb[u] = yp[tt * NCLS + (NCLS - 1)]; \
      pl[u] = yp[tt * NCLS + lab]; \
    } } while (0)

  // One DP step. Only ONE cross-lane value needed: alpha[2l-1] = a1(l-1).
#define STEP(pbv, plv) do { \
    const float lpb = FLOG2((pbv) + EPSF); \
    const float lpl = FLOG2((plv) + EPSF); \
    float a1u = __shfl_up(a1, 1); \
    if (lane == 0) a1u = NEGF; \
    /* even s=2l: lse2(a0, a1u) + lpb */ \
    const float m0 = fmaxf(a0, a1u); \
    const float n0 = m0 + FLOG2(1.0f + FEXP2(-fabsf(a0 - a1u))) + lpb; \
    /* odd s=2l+1: lse3(a1, a0, allow ? a1u : NEG) + lpl */ \
    const float a3 = allow ? a1u : NEGF; \
    const float m1 = fmaxf(fmaxf(a1, a0), a3); \
    const float s1 = FEXP2(a1 - m1) + FEXP2(a0 - m1) + FEXP2(a3 - m1); \
    const float n1 = m1 + FLOG2(s1) + lpl; \
    /* s=128 (lane 63 only, computed uniformly): lse2(a2, a1) + lpb */ \
    const float m2 = fmaxf(a2, a1); \
    const float n2 = m2 + FLOG2(1.0f + FEXP2(-fabsf(a2 - a1))) + lpb; \
    a0 = n0; a1 = n1; a2 = n2; \
  } while (0)

#define COMPC(pb, pl) do { \
    _Pragma("unroll") \
    for (int u = 0; u < UU; ++u) STEP(pb[u], pl[u]); \
  } while (0)

  LOADC(pbA, plA, 0);        // chunk 0: t = 0..15
  LOADC(pbB, plB, UU);       // chunk 1: t = 16..31

  // chunk 0: init at t=0, then steps t=1..15
  {
    const float lpb0 = FLOG2(pbA[0] + EPSF);
    const float lpl0 = FLOG2(plA[0] + EPSF);
    a0 = (lane == 0) ? lpb0 : NEGF;   // alpha0[0] = lp(blank, t=0)
    a1 = (lane == 0) ? lpl0 : NEGF;   // alpha0[1] = lp(label0, t=0)  (len>=16 so valid)
    a2 = NEGF;
#pragma unroll
    for (int u = 1; u < UU; ++u) STEP(pbA[u], plA[u]);
  }
  LOADC(pbA, plA, 2 * UU);
  COMPC(pbB, plB);
  LOADC(pbB, plB, 3 * UU);

#pragma unroll 1
  for (int cp = 1; cp < (TSTEPS / UU) / 2 - 1; ++cp) {   // cp = 1..14
    COMPC(pbA, plA);
    LOADC(pbA, plA, (2 * cp + 2) * UU);
    COMPC(pbB, plB);
    LOADC(pbB, plB, (2 * cp + 3) * UU);
  }
  COMPC(pbA, plA);           // chunk 30: t = 480..495
  COMPC(pbB, plB);           // chunk 31: t = 496..511

  // total ll = lse(alpha[2*len], alpha[2*len-1]); s=2len is a2 iff len==64
  const float x1 = (len >= LMAX) ? __shfl(a2, 63) : __shfl(a0, len);
  const float x2 = __shfl(a1, len - 1);
  const float mm  = fmaxf(x1, x2);
  const float ll2 = mm + FLOG2(FEXP2(x1 - mm) + FEXP2(x2 - mm));
  if (lane == 0) out[b] = -ll2 * 0.69314718055994530942f;

#undef LOADC
#undef STEP
#undef COMPC
}

extern "C" void kernel_launch(void* const* d_in, const int* in_sizes, int n_in,
                              void* d_out, int out_size, void* d_ws, size_t ws_size,
                              hipStream_t stream) {
  const int*   y_true = (const int*)d_in[0];
  const float* y_pred = (const float*)d_in[1];
  float*       out    = (float*)d_out;
  hipLaunchKernelGGL(ctc_kernel, dim3(512), dim3(64), 0, stream,
                     y_true, y_pred, out);
}

// Round 2
// 63.532 us; speedup vs baseline: 1.0316x; 1.0316x over previous
//
#include <hip/hip_runtime.h>

// CTC forward loss, B=512, T=512, C=81 (blank=80), L=64, S=129.
// One wave per batch element; lane l holds states 2l (a0), 2l+1 (a1);
// lane 63 also holds state 128 (a2). Log2-domain; *ln2 at end.
// Inline-asm prefetch pipeline: 4 rotating 8-step chunks, 3 chunks in flight,
// s_waitcnt vmcnt(32) per chunk (never 0 in steady state).

#define TSTEPS 512
#define NCLS   81
#define ROWB   324           // NCLS*4 bytes per t-row
#define LMAX   64
#define PADTOK 99
#define NEGF   (-1e30f)
#define EPSF   1e-7f
#define UU     8             // steps per chunk
#define CHB    (UU * ROWB)   // 2592 bytes per chunk

#if __has_builtin(__builtin_amdgcn_exp2f)
#define FEXP2 __builtin_amdgcn_exp2f
#else
#define FEXP2 exp2f
#endif
#if __has_builtin(__builtin_amdgcn_logf)
#define FLOG2 __builtin_amdgcn_logf
#else
#define FLOG2 log2f
#endif

// one scalar global load with literal offset; volatile => cannot be sunk
#define GL(dst, p, OFF) \
  asm volatile("global_load_dword %0, %1, off offset:" #OFF : "=v"(dst) : "v"(p))

#define LOADC(BB, LL) do { \
    GL(BB[0], pbp, 0);    GL(LL[0], plp, 0); \
    GL(BB[1], pbp, 324);  GL(LL[1], plp, 324); \
    GL(BB[2], pbp, 648);  GL(LL[2], plp, 648); \
    GL(BB[3], pbp, 972);  GL(LL[3], plp, 972); \
    GL(BB[4], pbp, 1296); GL(LL[4], plp, 1296); \
    GL(BB[5], pbp, 1620); GL(LL[5], plp, 1620); \
    GL(BB[6], pbp, 1944); GL(LL[6], plp, 1944); \
    GL(BB[7], pbp, 2268); GL(LL[7], plp, 2268); \
    pbp += CHB; plp += CHB; \
  } while (0)

// counted wait + scheduler fence (guide rule #18)
#define WAITV(N) do { \
    asm volatile("s_waitcnt vmcnt(" #N ")" ::: "memory"); \
    __builtin_amdgcn_sched_barrier(0); \
  } while (0)

// pin loaded regs: consumers must stay below the wait
#define PIN(BB, LL) \
  asm volatile("" : "+v"(BB[0]), "+v"(BB[1]), "+v"(BB[2]), "+v"(BB[3]), \
                    "+v"(BB[4]), "+v"(BB[5]), "+v"(BB[6]), "+v"(BB[7]), \
                    "+v"(LL[0]), "+v"(LL[1]), "+v"(LL[2]), "+v"(LL[3]), \
                    "+v"(LL[4]), "+v"(LL[5]), "+v"(LL[6]), "+v"(LL[7]))

// one DP step; only cross-lane value needed: alpha[2l-1] = a1(l-1)
#define STEP(pbv, plv) do { \
    const float lpb = FLOG2((pbv) + EPSF); \
    const float lpl = FLOG2((plv) + EPSF); \
    float a1u = __shfl_up(a1, 1); \
    a1u = lane0 ? NEGF : a1u; \
    /* even s=2l: lse2(a0, a1u) + lpb */ \
    const float m0 = fmaxf(a0, a1u); \
    const float n0 = m0 + FLOG2(1.0f + FEXP2(-fabsf(a0 - a1u))) + lpb; \
    /* odd s=2l+1: lse3(a1, a0, allow?a1u:NEG) + lpl ; lpl off-chain */ \
    const float a3 = allow ? a1u : NEGF; \
    const float m1 = fmaxf(fmaxf(a1, a0), a3); \
    const float s1 = FEXP2(a1 - m1) + FEXP2(a0 - m1) + FEXP2(a3 - m1); \
    const float n1 = FLOG2(s1) + (m1 + lpl); \
    /* s=128: lse2(a2, a1) + lpb (uniform; only read when len==64) */ \
    const float m2 = fmaxf(a2, a1); \
    const float n2 = m2 + FLOG2(1.0f + FEXP2(-fabsf(a2 - a1))) + lpb; \
    a0 = n0; a1 = n1; a2 = n2; \
  } while (0)

#define COMP(BB, LL) do { \
    _Pragma("unroll") \
    for (int u = 0; u < UU; ++u) STEP(BB[u], LL[u]); \
  } while (0)

__global__ __launch_bounds__(64) void ctc_kernel(
    const int* __restrict__ y_true, const float* __restrict__ y_pred,
    float* __restrict__ out)
{
  const int b    = blockIdx.x;
  const int lane = threadIdx.x;
  const char* yp = (const char*)(y_pred + (size_t)b * (TSTEPS * NCLS));

  const int  yt  = y_true[b * LMAX + lane];
  const bool mk  = (yt != PADTOK);
  const int  len = __popcll(__ballot(mk));
  const int  lab = mk ? yt : 0;
  const int  labu  = __shfl_up(lab, 1);
  const bool allow = (lane >= 1) && (lab != labu);
  const bool lane0 = (lane == 0);

  const char* pbp = yp + 320;        // blank col (80) base
  const char* plp = yp + lab * 4;    // per-lane label col base

  float a0, a1, a2;
  float bA[UU], lA[UU], bB[UU], lB[UU], bC[UU], lC[UU], bD[UU], lD[UU];

  LOADC(bA, lA);                     // chunk 0
  LOADC(bB, lB);                     // chunk 1
  LOADC(bC, lC);                     // chunk 2

  // ---- peeled iter 0 (init at t=0) : chunks 0..3 ----
  WAITV(32); PIN(bA, lA); LOADC(bD, lD);
  {
    const float lpb0 = FLOG2(bA[0] + EPSF);
    const float lpl0 = FLOG2(lA[0] + EPSF);
    a0 = lane0 ? lpb0 : NEGF;        // alpha0[0]
    a1 = lane0 ? lpl0 : NEGF;        // alpha0[1] (len>=16 so valid)
    a2 = NEGF;
#pragma unroll
    for (int u = 1; u < UU; ++u) STEP(bA[u], lA[u]);
  }
  WAITV(32); PIN(bB, lB); LOADC(bA, lA); COMP(bB, lB);
  WAITV(32); PIN(bC, lC); LOADC(bB, lB); COMP(bC, lC);
  WAITV(32); PIN(bD, lD); LOADC(bC, lC); COMP(bD, lD);

  // ---- steady state: chunks 4..59 ----
#pragma unroll 1
  for (int i = 1; i < 15; ++i) {
    WAITV(32); PIN(bA, lA); LOADC(bD, lD); COMP(bA, lA);
    WAITV(32); PIN(bB, lB); LOADC(bA, lA); COMP(bB, lB);
    WAITV(32); PIN(bC, lC); LOADC(bB, lB); COMP(bC, lC);
    WAITV(32); PIN(bD, lD); LOADC(bC, lC); COMP(bD, lD);
  }

  // ---- tail: chunks 60..63 (last issue = chunk 63 into D) ----
  WAITV(32); PIN(bA, lA); LOADC(bD, lD); COMP(bA, lA);
  WAITV(32); PIN(bB, lB); COMP(bB, lB);
  WAITV(16); PIN(bC, lC); COMP(bC, lC);
  WAITV(0);  PIN(bD, lD); COMP(bD, lD);

  // ll = lse(alpha[2*len], alpha[2*len-1]); s=2len is a2 iff len==64
  const float x1 = (len >= LMAX) ? __shfl(a2, 63) : __shfl(a0, len);
  const float x2 = __shfl(a1, len - 1);
  const float mm  = fmaxf(x1, x2);
  const float ll2 = mm + FLOG2(FEXP2(x1 - mm) + FEXP2(x2 - mm));
  if (lane == 0) out[b] = -ll2 * 0.69314718055994530942f;
}

extern "C" void kernel_launch(void* const* d_in, const int* in_sizes, int n_in,
                              void* d_out, int out_size, void* d_ws, size_t ws_size,
                              hipStream_t stream) {
  const int*   y_true = (const int*)d_in[0];
  const float* y_pred = (const float*)d_in[1];
  float*       out    = (float*)d_out;
  hipLaunchKernelGGL(ctc_kernel, dim3(512), dim3(64), 0, stream,
                     y_true, y_pred, out);
}

// Round 4
// 28.923 us; speedup vs baseline: 2.2660x; 2.1966x over previous
//
#include <hip/hip_runtime.h>

// CTC forward loss, B=512, T=512, C=81 (blank=80), L=64, S=2len+1.
// One wave per batch element; lane l holds states 2l (a0), 2l+1 (a1);
// lane 63 also holds state 128 (a2, only if len==64).
// LINEAR-domain alpha in f64 (probs f32), exact power-of-2 Rabiner rescale
// every 32 steps via int-hi-word DPP max tree. Garbage states (s>2len) held
// at exactly 0 by masking a1 with (lane<len) each step -- they are seeded
// only through state 2len+1, so this keeps the whole invalid region zero.
// Cross-lane alpha[2l-1] via DPP wave_shr:1 on both halves (VALU, not LDS).
// Inline-asm prefetch: 4 rotating 8-step chunks, vmcnt(32) counted waits.

#define TSTEPS 512
#define NCLS   81
#define ROWB   324
#define LMAX   64
#define PADTOK 99
#define EPSF   1e-7f
#define UU     8
#define CHB    (UU * ROWB)

#if __has_builtin(__builtin_amdgcn_logf)
#define FLOG2 __builtin_amdgcn_logf
#else
#define FLOG2 log2f
#endif

__device__ __forceinline__ double dpp_shr1_f64(double x) {
  unsigned long long u = __builtin_bit_cast(unsigned long long, x);
  int lo = __builtin_amdgcn_update_dpp(0, (int)u,         0x138, 0xF, 0xF, true);
  int hi = __builtin_amdgcn_update_dpp(0, (int)(u >> 32), 0x138, 0xF, 0xF, true);
  unsigned long long r = ((unsigned long long)(unsigned)hi << 32) | (unsigned)lo;
  return __builtin_bit_cast(double, r);   // lane0 -> +0.0 (linear-domain -inf)
}

template <int CTRL>
__device__ __forceinline__ int dppmaxi(int x) {
  int y = __builtin_amdgcn_update_dpp(0, x, CTRL, 0xF, 0xF, true);
  return x > y ? x : y;   // hi-words of positive doubles: int max == value max
}

__device__ __forceinline__ double andm(double x, long long m) {
  return __builtin_bit_cast(double, __builtin_bit_cast(long long, x) & m);
}

#define GL(dst, p, OFF) \
  asm volatile("global_load_dword %0, %1, off offset:" #OFF : "=v"(dst) : "v"(p))

#define LOADC(BB, LL) do { \
    GL(BB[0], pbp, 0);    GL(LL[0], plp, 0); \
    GL(BB[1], pbp, 324);  GL(LL[1], plp, 324); \
    GL(BB[2], pbp, 648);  GL(LL[2], plp, 648); \
    GL(BB[3], pbp, 972);  GL(LL[3], plp, 972); \
    GL(BB[4], pbp, 1296); GL(LL[4], plp, 1296); \
    GL(BB[5], pbp, 1620); GL(LL[5], plp, 1620); \
    GL(BB[6], pbp, 1944); GL(LL[6], plp, 1944); \
    GL(BB[7], pbp, 2268); GL(LL[7], plp, 2268); \
    pbp += CHB; plp += CHB; \
  } while (0)

#define WAITV(N) asm volatile("s_waitcnt vmcnt(" #N ")" ::: "memory")

#define PIN(BB, LL) \
  asm volatile("" : "+v"(BB[0]), "+v"(BB[1]), "+v"(BB[2]), "+v"(BB[3]), \
                    "+v"(BB[4]), "+v"(BB[5]), "+v"(BB[6]), "+v"(BB[7]), \
                    "+v"(LL[0]), "+v"(LL[1]), "+v"(LL[2]), "+v"(LL[3]), \
                    "+v"(LL[4]), "+v"(LL[5]), "+v"(LL[6]), "+v"(LL[7]))

// n0=(a0+a1u)*qb ; n1=((a1+a0)+a3)*ql masked ; n2=(a2+a1)*qb (len==64 only)
#define STEP(pbv, plv) do { \
    const double qb  = (double)((pbv) + EPSF); \
    const double ql  = (double)((plv) + EPSF); \
    const double a1u = dpp_shr1_f64(a1); \
    const double a3  = andm(a1u, allowm); \
    const double n0  = (a0 + a1u) * qb; \
    const double n1  = andm(((a1 + a0) + a3) * ql, validm); \
    if (full) a2 = (a2 + a1) * qb; \
    a0 = n0; a1 = n1; \
  } while (0)

#define COMP(BB, LL) do { \
    _Pragma("unroll") \
    for (int u = 0; u < UU; ++u) STEP(BB[u], LL[u]); \
  } while (0)

// exact 2^k rescale; k from wave-max hi-word exponent (DPP tree -> lane 63)
#define RESCALE do { \
    double mx = fmax(fmax(a0, a1), a2); \
    int mh = (int)(__builtin_bit_cast(unsigned long long, mx) >> 32); \
    mh = dppmaxi<0x111>(mh); \
    mh = dppmaxi<0x112>(mh); \
    mh = dppmaxi<0x114>(mh); \
    mh = dppmaxi<0x118>(mh); \
    mh = dppmaxi<0x142>(mh); \
    mh = dppmaxi<0x143>(mh); \
    const int hb = __builtin_amdgcn_readlane(mh, 63); \
    const int ef = (hb >> 20) & 0x7FF; \
    const double sc = __builtin_bit_cast(double, \
                        (unsigned long long)(2046 - ef) << 52); \
    a0 *= sc; a1 *= sc; a2 *= sc; \
    Esum += ef - 1023; \
  } while (0)

__global__ __launch_bounds__(64, 1) void ctc_kernel(
    const int* __restrict__ y_true, const float* __restrict__ y_pred,
    float* __restrict__ out)
{
  const int b    = blockIdx.x;
  const int lane = threadIdx.x;
  const char* yp = (const char*)(y_pred + (size_t)b * (TSTEPS * NCLS));

  const int  yt  = y_true[b * LMAX + lane];
  const bool mk  = (yt != PADTOK);
  const int  len = __popcll(__ballot(mk));
  const int  lab = mk ? yt : 0;
  const int  labu = __shfl_up(lab, 1);
  const long long allowm = ((lane >= 1) && (lab != labu)) ? -1LL : 0LL;
  const long long validm = (lane < len) ? -1LL : 0LL;   // a1 (s=2l+1) valid iff l<len
  const bool lane0 = (lane == 0);
  const bool full  = (len == LMAX);

  const char* pbp = yp + 320;        // blank col (80)
  const char* plp = yp + lab * 4;    // per-lane label col

  double a0, a1, a2;
  int Esum = 0;
  float bA[UU], lA[UU], bB[UU], lB[UU], bC[UU], lC[UU], bD[UU], lD[UU];

  LOADC(bA, lA);   // chunk 0
  LOADC(bB, lB);   // chunk 1
  LOADC(bC, lC);   // chunk 2

  // peeled chunk 0 (init at t=0)
  WAITV(32); PIN(bA, lA); LOADC(bD, lD);
  {
    a0 = lane0 ? (double)(bA[0] + EPSF) : 0.0;   // alpha0[0]
    a1 = lane0 ? (double)(lA[0] + EPSF) : 0.0;   // alpha0[1] (len>=16)
    a2 = 0.0;
#pragma unroll
    for (int u = 1; u < UU; ++u) STEP(bA[u], lA[u]);
  }
  WAITV(32); PIN(bB, lB); LOADC(bA, lA); COMP(bB, lB);
  WAITV(32); PIN(bC, lC); LOADC(bB, lB); COMP(bC, lC);
  WAITV(32); PIN(bD, lD); LOADC(bC, lC); COMP(bD, lD);
  RESCALE;

  // steady state: chunks 4..59 ; rescale every 32 steps
#pragma unroll 1
  for (int i = 1; i < 15; ++i) {
    WAITV(32); PIN(bA, lA); LOADC(bD, lD); COMP(bA, lA);
    WAITV(32); PIN(bB, lB); LOADC(bA, lA); COMP(bB, lB);
    WAITV(32); PIN(bC, lC); LOADC(bB, lB); COMP(bC, lC);
    WAITV(32); PIN(bD, lD); LOADC(bC, lC); COMP(bD, lD);
    RESCALE;
  }

  // tail: chunks 60..63 (decay <= ~2^-300 from last rescale: safe in f64)
  WAITV(32); PIN(bA, lA); LOADC(bD, lD); COMP(bA, lA);
  WAITV(32); PIN(bB, lB); COMP(bB, lB);
  WAITV(16); PIN(bC, lC); COMP(bC, lC);
  WAITV(0);  PIN(bD, lD); COMP(bD, lD);

  // ll = log2(alpha[2len] + alpha[2len-1]) + Esum ; 2len is a2 iff len==64
  const double x1 = full ? __shfl(a2, 63) : __shfl(a0, len);
  const double x2 = __shfl(a1, len - 1);
  const double s  = x1 + x2;
  const unsigned long long sb = __builtin_bit_cast(unsigned long long, s);
  const int    e2   = (int)((sb >> 52) & 0x7FF) - 1023;
  const double mant = __builtin_bit_cast(double,
      (sb & 0x000FFFFFFFFFFFFFULL) | 0x3FF0000000000000ULL);   // [1,2)
  const float  ll2  = FLOG2((float)mant) + (float)(e2 + Esum);
  if (lane0) out[b] = -ll2 * 0.69314718055994530942f;
}

extern "C" void kernel_launch(void* const* d_in, const int* in_sizes, int n_in,
                              void* d_out, int out_size, void* d_ws, size_t ws_size,
                              hipStream_t stream) {
  const int*   y_true = (const int*)d_in[0];
  const float* y_pred = (const float*)d_in[1];
  float*       out    = (float*)d_out;
  hipLaunchKernelGGL(ctc_kernel, dim3(512), dim3(64), 0, stream,
                     y_true, y_pred, out);
}

// Round 5
// 24.594 us; speedup vs baseline: 2.6649x; 1.1760x over previous
//
#include <hip/hip_runtime.h>

// CTC forward loss, B=512, T=512, C=81 (blank=80), L=64.
// One BLOCK (128 thr = 2 waves) per batch element.
//   wave0: forward alpha over t=0..255   (alpha_{t} = D(q_t) A alpha_{t-1})
//   wave1: backward gamma over t=511..256 (gamma^T = f^T prod D(q_t) A)
//   ll = sum_s gamma[s]*alpha[s]  (combined via LDS after barrier)
// Lane l holds states 2l, 2l+1 (+ s=128 on lane 63). LINEAR-domain f64 with
// exact power-of-2 Rabiner rescale every 32 steps (int-hi-word DPP max tree).
// Invalid states (s>2len) held at exactly 0 by masking the odd state with
// (lane<len); both recursions provably never re-seed the invalid region.
// Cross-lane via DPP wave_shr:1 (fwd) / wave_shl:1 (bwd) -- pure VALU.
// Inline-asm prefetch: 4 rotating 8-row chunks, vmcnt(32) counted waits.

#define TSTEPS 512
#define NCLS   81
#define ROWB   324
#define LMAX   64
#define PADTOK 99
#define EPSF   1e-7f
#define UU     8
#define CHB    (UU * ROWB)

#if __has_builtin(__builtin_amdgcn_logf)
#define FLOG2 __builtin_amdgcn_logf
#else
#define FLOG2 log2f
#endif

__device__ __forceinline__ double dpp_shr1_f64(double x) {   // lane l <- l-1, lane0 -> 0
  unsigned long long u = __builtin_bit_cast(unsigned long long, x);
  int lo = __builtin_amdgcn_update_dpp(0, (int)u,         0x138, 0xF, 0xF, true);
  int hi = __builtin_amdgcn_update_dpp(0, (int)(u >> 32), 0x138, 0xF, 0xF, true);
  unsigned long long r = ((unsigned long long)(unsigned)hi << 32) | (unsigned)lo;
  return __builtin_bit_cast(double, r);
}
__device__ __forceinline__ double dpp_shl1_f64(double x) {   // lane l <- l+1, lane63 -> 0
  unsigned long long u = __builtin_bit_cast(unsigned long long, x);
  int lo = __builtin_amdgcn_update_dpp(0, (int)u,         0x130, 0xF, 0xF, true);
  int hi = __builtin_amdgcn_update_dpp(0, (int)(u >> 32), 0x130, 0xF, 0xF, true);
  unsigned long long r = ((unsigned long long)(unsigned)hi << 32) | (unsigned)lo;
  return __builtin_bit_cast(double, r);
}
template <int CTRL>
__device__ __forceinline__ int dppmaxi(int x) {
  int y = __builtin_amdgcn_update_dpp(0, x, CTRL, 0xF, 0xF, true);
  return x > y ? x : y;
}
__device__ __forceinline__ double andm(double x, long long m) {
  return __builtin_bit_cast(double, __builtin_bit_cast(long long, x) & m);
}

#define GL(dst, p, OFF) \
  asm volatile("global_load_dword %0, %1, off offset:" #OFF : "=v"(dst) : "v"(p))

#define LOADBODY(BB, LL) \
    GL(BB[0], pbp, 0);    GL(LL[0], plp, 0); \
    GL(BB[1], pbp, 324);  GL(LL[1], plp, 324); \
    GL(BB[2], pbp, 648);  GL(LL[2], plp, 648); \
    GL(BB[3], pbp, 972);  GL(LL[3], plp, 972); \
    GL(BB[4], pbp, 1296); GL(LL[4], plp, 1296); \
    GL(BB[5], pbp, 1620); GL(LL[5], plp, 1620); \
    GL(BB[6], pbp, 1944); GL(LL[6], plp, 1944); \
    GL(BB[7], pbp, 2268); GL(LL[7], plp, 2268);

#define LOADCF(BB, LL) do { LOADBODY(BB, LL) pbp += CHB; plp += CHB; } while (0)
#define LOADCB(BB, LL) do { LOADBODY(BB, LL) pbp -= CHB; plp -= CHB; } while (0)

#define WAITV(N) asm volatile("s_waitcnt vmcnt(" #N ")" ::: "memory")

#define PIN(BB, LL) \
  asm volatile("" : "+v"(BB[0]), "+v"(BB[1]), "+v"(BB[2]), "+v"(BB[3]), \
                    "+v"(BB[4]), "+v"(BB[5]), "+v"(BB[6]), "+v"(BB[7]), \
                    "+v"(LL[0]), "+v"(LL[1]), "+v"(LL[2]), "+v"(LL[3]), \
                    "+v"(LL[4]), "+v"(LL[5]), "+v"(LL[6]), "+v"(LL[7]))

// ---- forward step (verified round 4): a2 now unconditional (==0 if len<64)
#define STEPF(pbv, plv) do { \
    const double qb  = (double)((pbv) + EPSF); \
    const double ql  = (double)((plv) + EPSF); \
    const double a1u = dpp_shr1_f64(a1); \
    const double a3  = andm(a1u, allowm); \
    const double n0  = (a0 + a1u) * qb; \
    const double n1  = andm(((a1 + a0) + a3) * ql, validm); \
    a2 = (a2 + a1) * qb; \
    a0 = n0; a1 = n1; \
  } while (0)

// ---- backward step: delta = gamma*q ; gamma'[s] = delta[s] + delta[s+1]
//      + allow[s+2]*delta[s+2]  (even s: lane-local; odd s: via wave_shl)
#define STEPB(pbv, plv) do { \
    const double qb = (double)((pbv) + EPSF); \
    const double ql = (double)((plv) + EPSF); \
    const double d0 = g0 * qb; \
    const double d1 = g1 * ql; \
    const double d2 = g2 * qb; \
    const double s0 = dpp_shl1_f64(d0); \
    const double s1 = dpp_shl1_f64(d1); \
    const double t1 = (d1 + (s0 + andm(d2, l63m))) + andm(s1, am_next); \
    g1 = andm(t1, validm); \
    g0 = d0 + d1; \
    g2 = d2; \
  } while (0)

#define COMPF(BB, LL) do { \
    _Pragma("unroll") for (int u = 0; u < UU; ++u) STEPF(BB[u], LL[u]); } while (0)
#define COMPB(BB, LL) do { \
    _Pragma("unroll") for (int u = UU - 1; u >= 0; --u) STEPB(BB[u], LL[u]); } while (0)

// exact 2^k rescale; k from wave-max hi-word exponent (values all >= 0)
#define RESCALE3(x, y, z, E) do { \
    double mx = fmax(fmax(x, y), z); \
    int mh = (int)(__builtin_bit_cast(unsigned long long, mx) >> 32); \
    mh = dppmaxi<0x111>(mh); \
    mh = dppmaxi<0x112>(mh); \
    mh = dppmaxi<0x114>(mh); \
    mh = dppmaxi<0x118>(mh); \
    mh = dppmaxi<0x142>(mh); \
    mh = dppmaxi<0x143>(mh); \
    const int hb = __builtin_amdgcn_readlane(mh, 63); \
    const int ef = (hb >> 20) & 0x7FF; \
    const double sc = __builtin_bit_cast(double, \
                        (unsigned long long)(2046 - ef) << 52); \
    x *= sc; y *= sc; z *= sc; \
    E += ef - 1023; \
  } while (0)

// 32-chunk pipeline: 3 in flight, counted vmcnt, rescale every 4 chunks
#define DRIVER(LOADM, COMPM, INITM, RESCM) do { \
    LOADM(bA, lA); LOADM(bB, lB); LOADM(bC, lC); \
    WAITV(32); PIN(bA, lA); LOADM(bD, lD); INITM; \
    WAITV(32); PIN(bB, lB); LOADM(bA, lA); COMPM(bB, lB); \
    WAITV(32); PIN(bC, lC); LOADM(bB, lB); COMPM(bC, lC); \
    WAITV(32); PIN(bD, lD); LOADM(bC, lC); COMPM(bD, lD); RESCM; \
    _Pragma("unroll 1") \
    for (int i = 1; i < 7; ++i) { \
      WAITV(32); PIN(bA, lA); LOADM(bD, lD); COMPM(bA, lA); \
      WAITV(32); PIN(bB, lB); LOADM(bA, lA); COMPM(bB, lB); \
      WAITV(32); PIN(bC, lC); LOADM(bB, lB); COMPM(bC, lC); \
      WAITV(32); PIN(bD, lD); LOADM(bC, lC); COMPM(bD, lD); RESCM; \
    } \
    WAITV(32); PIN(bA, lA); LOADM(bD, lD); COMPM(bA, lA); \
    WAITV(32); PIN(bB, lB); COMPM(bB, lB); \
    WAITV(16); PIN(bC, lC); COMPM(bC, lC); \
    WAITV(0);  PIN(bD, lD); COMPM(bD, lD); RESCM; \
  } while (0)

#define INITF do { \
    a0 = lane0 ? (double)(bA[0] + EPSF) : 0.0; \
    a1 = lane0 ? (double)(lA[0] + EPSF) : 0.0; \
    a2 = 0.0; \
    _Pragma("unroll") for (int u = 1; u < UU; ++u) STEPF(bA[u], lA[u]); \
  } while (0)

#define INITB do { \
    g0 = (lane == len)     ? 1.0 : 0.0;   /* s=2len   (never when len==64) */ \
    g1 = (lane == len - 1) ? 1.0 : 0.0;   /* s=2len-1 */ \
    g2 = (full && lane == 63) ? 1.0 : 0.0; /* s=128 when len==64 */ \
    _Pragma("unroll") for (int u = UU - 1; u >= 0; --u) STEPB(bA[u], lA[u]); \
  } while (0)

__global__ __launch_bounds__(128, 1) void ctc_kernel(
    const int* __restrict__ y_true, const float* __restrict__ y_pred,
    float* __restrict__ out)
{
  const int b    = blockIdx.x;
  const int tid  = threadIdx.x;
  const int lane = tid & 63;
  const int wv   = tid >> 6;
  const char* yp = (const char*)(y_pred + (size_t)b * (TSTEPS * NCLS));

  const int  yt  = y_true[b * LMAX + lane];
  const bool mk  = (yt != PADTOK);
  const int  len = __popcll(__ballot(mk));
  const int  lab = mk ? yt : 0;
  const int  labu   = __shfl_up(lab, 1);
  const int  allowi = ((lane >= 1) && (lab != labu)) ? 1 : 0;
  const int  allown = __shfl_down(allowi, 1);
  const long long allowm  = allowi ? -1LL : 0LL;
  const long long am_next = allown ? -1LL : 0LL;
  const long long validm  = (lane < len) ? -1LL : 0LL;
  const long long l63m    = (lane == 63) ? -1LL : 0LL;
  const bool lane0 = (lane == 0);
  const bool full  = (len == LMAX);

  __shared__ double sh[129];
  __shared__ int    shE;

  double a0, a1, a2;          // forward states
  double g0, g1, g2;          // backward states
  int Ef = 0, Eb = 0;
  float bA[UU], lA[UU], bB[UU], lB[UU], bC[UU], lC[UU], bD[UU], lD[UU];

  if (wv == 0) {
    // forward: rows 0..255
    const char* pbp = yp + 320;
    const char* plp = yp + lab * 4;
    DRIVER(LOADCF, COMPF, INITF, RESCALE3(a0, a1, a2, Ef));
    sh[lane]      = a0;
    sh[64 + lane] = a1;
    if (lane == 63) sh[128] = a2;
    if (lane0)      shE     = Ef;
  } else {
    // backward: rows 511..256 (chunk base row 504, descending)
    const char* pbp = yp + 504 * ROWB + 320;
    const char* plp = yp + 504 * ROWB + lab * 4;
    DRIVER(LOADCB, COMPB, INITB, RESCALE3(g0, g1, g2, Eb));
  }

  __syncthreads();

  if (wv == 1) {
    double p = g0 * sh[lane] + g1 * sh[64 + lane];
    p += andm(g2 * sh[128], l63m);
#pragma unroll
    for (int off = 32; off; off >>= 1) p += __shfl_xor(p, off);
    if (lane0) {
      const unsigned long long sb = __builtin_bit_cast(unsigned long long, p);
      const int    e2   = (int)((sb >> 52) & 0x7FF) - 1023;
      const double mant = __builtin_bit_cast(double,
          (sb & 0x000FFFFFFFFFFFFFULL) | 0x3FF0000000000000ULL);
      const float  ll2  = FLOG2((float)mant) + (float)(e2 + Ef + Eb + shE - Ef);
      out[b] = -ll2 * 0.69314718055994530942f;
    }
  }
}

extern "C" void kernel_launch(void* const* d_in, const int* in_sizes, int n_in,
                              void* d_out, int out_size, void* d_ws, size_t ws_size,
                              hipStream_t stream) {
  const int*   y_true = (const int*)d_in[0];
  const float* y_pred = (const float*)d_in[1];
  float*       out    = (float*)d_out;
  hipLaunchKernelGGL(ctc_kernel, dim3(512), dim3(128), 0, stream,
                     y_true, y_pred, out);
}